// Round 5
// baseline (8279.253 us; speedup 1.0000x reference)
//
#include <hip/hip_runtime.h>

// PopulationODE: sequential RK4 scan, T=4096, state=4, HID=32.
// One wave64, weights + state in registers, zero LDS, zero scratch.
// Cross-lane via DPP row_ror and v_permlane16/32_swap_b32 only.
//
// Round-5 changes vs round-3 (proven) base:
//  - amdgpu_waves_per_eu(1,1): occupancy TARGET 1 wave/EU -> 512-VGPR
//    budget -> 64 weights stay in plain VGPRs (VOP2-DPP fusable).
//    (Round 4's failure bundled this with asm pins; pins dropped.)
//  - s_nop 1 hardening inside permlane asm (VALU-write->permlane-read
//    hazard cannot be auto-managed inside inline asm).
//  - Algebra: tanh/sigmoid input scales pre-folded into weights,
//    head bias folded into per-lane fmaf, zs hoisted per step, z tree.
//
// Layouts (m = lane>>4 row, i = lane&15):
//   ABAB: lane holds v[16*(m&1) + i]
//   AABB: lane holds v[16*(m>>1) + i]
// matvec_A: ABAB -> AABB (combine rows m^1 via p16swap)
// matvec_B: AABB -> ABAB (combine rows m^2 via p32swap)

__device__ __forceinline__ float fexp2(float x) { return __builtin_amdgcn_exp2f(x); }
__device__ __forceinline__ float frcp(float x) { return __builtin_amdgcn_rcpf(x); }
// Inputs to these are PRE-SCALED: tanh path by 2*log2(e), sigm path by -log2(e).
__device__ __forceinline__ float ftanh_pre(float zs) {  // tanh(z), zs = 2*log2e*z
  float e = fexp2(zs);
  return 1.0f - 2.0f * frcp(e + 1.0f);
}
__device__ __forceinline__ float fsigm_pre(float zs) {  // sigm(z), zs = -log2e*z
  return frcp(1.0f + fexp2(zs));
}
__device__ __forceinline__ float fsigm(float a) {       // raw-input sigmoid
  return frcp(1.0f + fexp2(a * -1.4426950408889634f));
}

#define C_TANH 2.8853900817779268f
#define C_NSIG (-1.4426950408889634f)

// mov_dpp with bound_ctrl=1, full masks: canonical fusable form.
template<int CTRL>
__device__ __forceinline__ float dppmov(float x) {
  return __int_as_float(__builtin_amdgcn_update_dpp(
      0, __float_as_int(x), CTRL, 0xF, 0xF, true));
}
#define RORc(K) (0x120 | (K))

// Permlane swaps with hazard wait-states (compiler can't see inside asm).
__device__ __forceinline__ void p16swap(float& a, float& b) {
  asm("s_nop 1\n\tv_permlane16_swap_b32 %0, %1" : "+v"(a), "+v"(b));
}
__device__ __forceinline__ void p32swap(float& a, float& b) {
  asm("s_nop 1\n\tv_permlane32_swap_b32 %0, %1" : "+v"(a), "+v"(b));
}

// 16 MACs: stream j handles rotation steps {j, j+4, j+8, j+12} from base.
#define MV_CORE(W, BZ, X, SOUT) do {                                   \
    float a0_ = fmaf((X),                 W[0],  (BZ));                \
    float a1_ = dppmov<RORc(1)>(X)      * W[1];                        \
    float a2_ = dppmov<RORc(2)>(X)      * W[2];                        \
    float a3_ = dppmov<RORc(3)>(X)      * W[3];                        \
    a0_ = fmaf(dppmov<RORc(4)>(X),  W[4],  a0_);                       \
    a1_ = fmaf(dppmov<RORc(5)>(X),  W[5],  a1_);                       \
    a2_ = fmaf(dppmov<RORc(6)>(X),  W[6],  a2_);                       \
    a3_ = fmaf(dppmov<RORc(7)>(X),  W[7],  a3_);                       \
    a0_ = fmaf(dppmov<RORc(8)>(X),  W[8],  a0_);                       \
    a1_ = fmaf(dppmov<RORc(9)>(X),  W[9],  a1_);                       \
    a2_ = fmaf(dppmov<RORc(10)>(X), W[10], a2_);                       \
    a3_ = fmaf(dppmov<RORc(11)>(X), W[11], a3_);                       \
    a0_ = fmaf(dppmov<RORc(12)>(X), W[12], a0_);                       \
    a1_ = fmaf(dppmov<RORc(13)>(X), W[13], a1_);                       \
    a2_ = fmaf(dppmov<RORc(14)>(X), W[14], a2_);                       \
    a3_ = fmaf(dppmov<RORc(15)>(X), W[15], a3_);                       \
    SOUT = (a0_ + a1_) + (a2_ + a3_);                                  \
  } while (0)

__global__ __launch_bounds__(64, 1) __attribute__((amdgpu_waves_per_eu(1, 1)))
void ode_kernel(const float* __restrict__ s_grid,
                const float* __restrict__ y0in,
                const float* __restrict__ Win,
                const float* __restrict__ bin_,
                const float* __restrict__ W1a, const float* __restrict__ b1a,
                const float* __restrict__ W1b, const float* __restrict__ b1b,
                const float* __restrict__ W2a, const float* __restrict__ b2a,
                const float* __restrict__ W2b, const float* __restrict__ b2b,
                const float* __restrict__ Wout, const float* __restrict__ bout,
                const float* __restrict__ Aarr,
                float* __restrict__ out, int T) {
  const int lane = threadIdx.x;   // 0..63
  const int i = lane & 15;
  const int m = lane >> 4;        // row 0..3
  const int mlo = m & 1;          // ABAB block / matvec_A col-block
  const int mhi = m >> 1;         // AABB block / matvec_B col-block

  // ---- one-time direction probes ----
  int delta;
  {
    float pr = (float)i;
    float pr1 = dppmov<RORc(1)>(pr);
    delta = (((int)pr1) - i) & 15;
  }
  bool p32_c_low;
  {
    float v = (float)(lane >> 5);
    float c = v, d = v;
    p32swap(c, d);
    p32_c_low = (c == 0.0f);
  }

  // ---- weights into registers (pre-scaled where they feed tanh/sigm) ----
  // matvec_A (input ABAB): out row rA = 16*mhi + i, col block hA = mlo
  // matvec_B (input AABB): out row rB = 16*mlo + i, col block hB = mhi
  const int rA = 16 * mhi + i, hA = mlo;
  const int rB = 16 * mlo + i, hB = mhi;
  float w1a[16], w1b[16], w2a[16], w2b[16];
#pragma unroll
  for (int k = 0; k < 16; ++k) {
    int cA = hA * 16 + ((i + delta * k) & 15);
    int cB = hB * 16 + ((i + delta * k) & 15);
    w1a[k] = W1a[rA * 32 + cA] * C_TANH;   // feeds tanh
    w2a[k] = W2a[rA * 32 + cA] * C_TANH;   // feeds tanh
    w1b[k] = W1b[rB * 32 + cB];            // linear (residual add)
    w2b[k] = W2b[rB * 32 + cB];
  }
  const int r_in = 16 * mlo + i;   // input layer produces ABAB (feeds tanh)
  float winy0 = Win[r_in * 5 + 0] * C_TANH;
  float winy1 = Win[r_in * 5 + 1] * C_TANH;
  float winy2 = Win[r_in * 5 + 2] * C_TANH;
  float winy3 = Win[r_in * 5 + 3] * C_TANH;
  float wins  = Win[r_in * 5 + 4] * C_TANH;
  float binr  = bin_[r_in] * C_TANH;
  float bz1a = hA ? 0.0f : b1a[rA] * C_TANH;
  float bz2a = hA ? 0.0f : b2a[rA] * C_TANH;
  float bz1b = hB ? 0.0f : b1b[rB];
  float bz2b = hB ? 0.0f : b2b[rB];

  // head: row m handles Wout rows {2*mhi, 2*mhi+1} over col block mlo.
  // Pre-scaled by -log2e (sigmoid); bias folded per-lane (/32 over reduction).
  float woA = Wout[(2 * mhi + 0) * 32 + 16 * mlo + i] * C_NSIG;
  float woB = Wout[(2 * mhi + 1) * 32 + 16 * mlo + i] * C_NSIG;
  float boa = (mhi ? bout[2] : bout[0]) * (C_NSIG / 32.0f);
  float bob = (mhi ? bout[3] : bout[1]) * (C_NSIG / 32.0f);
  float Aa = mhi ? Aarr[2] : Aarr[0];
  float Ab = mhi ? Aarr[3] : Aarr[1];
  const bool selhi = (mhi != 0);

  auto matvecA = [&](const float (&w)[16], float bz, float xin) -> float {
    float s;
    MV_CORE(w, bz, xin, s);
    float b = s;
    p16swap(s, b);
    return s + b;                  // AABB
  };
  auto matvecB = [&](const float (&w)[16], float bz, float xin) -> float {
    float s;
    MV_CORE(w, bz, xin, s);
    float b = s;
    p32swap(s, b);
    return s + b;                  // ABAB
  };

  auto feval = [&](float YA, float YB, float YC, float YD, float ZS,
                   float& K0, float& K1, float& K2, float& K3) {
    // off-critical-path: prefactors for this lane's two components
    float Ya = selhi ? YC : YA;
    float Yb = selhi ? YD : YB;
    float s_a = fsigm(Ya), s_b = fsigm(Yb);
    float pref_a = 0.01f * s_a * (Aa - s_a);
    float pref_b = 0.01f * s_b * (Ab - s_b);
    // critical path: z tree (ZS = wins*sp + binr, hoisted per step)
    float za = fmaf(winy0, YA, ZS);
    float zb = winy1 * YB;
    float zc = winy2 * YC;
    float zd = winy3 * YD;
    float z = (za + zb) + (zc + zd);
    float x = ftanh_pre(z);                   // ABAB
    float u1 = matvecA(w1a, bz1a, x);         // AABB
    float t1 = ftanh_pre(u1);
    float v1 = matvecB(w1b, bz1b, t1);        // ABAB
    float x2 = x + v1;
    float u2 = matvecA(w2a, bz2a, x2);        // AABB
    float t2 = ftanh_pre(u2);
    float v2 = matvecB(w2b, bz2b, t2);        // ABAB
    float x3 = x2 + v2;
    // head (weights pre-scaled by -log2e, bias folded per-lane)
    float p0 = fmaf(woA, x3, boa);
    float p1 = fmaf(woB, x3, bob);
    p0 += dppmov<RORc(8)>(p0); p1 += dppmov<RORc(8)>(p1);
    p0 += dppmov<RORc(4)>(p0); p1 += dppmov<RORc(4)>(p1);
    p0 += dppmov<RORc(2)>(p0); p1 += dppmov<RORc(2)>(p1);
    p0 += dppmov<RORc(1)>(p0); p1 += dppmov<RORc(1)>(p1);
    float q0 = p0; p16swap(p0, q0); p0 += q0;  // rows0,1:P0'  rows2,3:P2'
    float q1 = p1; p16swap(p1, q1); p1 += q1;  // rows0,1:P1'  rows2,3:P3'
    float n_a = fsigm_pre(p0);
    float n_b = fsigm_pre(p1);
    float Ka = pref_a * n_a;     // rows0,1: K0   rows2,3: K2
    float Kb = pref_b * n_b;     // rows0,1: K1   rows2,3: K3
    float c0 = Ka, d0 = Ka; p32swap(c0, d0);
    K0 = p32_c_low ? c0 : d0;
    K2 = p32_c_low ? d0 : c0;
    float c1 = Kb, d1 = Kb; p32swap(c1, d1);
    K1 = p32_c_low ? c1 : d1;
    K3 = p32_c_low ? d1 : c1;
  };

  // ---- state ----
  float y0v = y0in[0], y1v = y0in[1], y2v = y0in[2], y3v = y0in[3];

  if (lane < 4) {
    float ov = (lane == 0) ? y0v : (lane == 1) ? y1v : (lane == 2) ? y2v : y3v;
    out[lane] = ov;
  }

  float sp = s_grid[0];
  float sn = s_grid[1];

  for (int t = 0; t < T - 1; ++t) {
    float snn = s_grid[(t + 2 < T) ? (t + 2) : (T - 1)];  // prefetch
    float h = sn - sp;
    float zs = fmaf(wins, sp, binr);   // shared by all 4 stages (s = s_prev)

    float k10, k11, k12, k13, k20, k21, k22, k23;
    float k30, k31, k32, k33, k40, k41, k42, k43;

    feval(y0v, y1v, y2v, y3v, zs, k10, k11, k12, k13);

    float hh = 0.5f * h;
    float ya0 = fmaf(hh, k10, y0v), ya1 = fmaf(hh, k11, y1v);
    float ya2 = fmaf(hh, k12, y2v), ya3 = fmaf(hh, k13, y3v);
    feval(ya0, ya1, ya2, ya3, zs, k20, k21, k22, k23);

    float yb0 = fmaf(hh, k20, y0v), yb1 = fmaf(hh, k21, y1v);
    float yb2 = fmaf(hh, k22, y2v), yb3 = fmaf(hh, k23, y3v);
    feval(yb0, yb1, yb2, yb3, zs, k30, k31, k32, k33);

    float yc0 = fmaf(h, k30, y0v), yc1 = fmaf(h, k31, y1v);
    float yc2 = fmaf(h, k32, y2v), yc3 = fmaf(h, k33, y3v);
    feval(yc0, yc1, yc2, yc3, zs, k40, k41, k42, k43);

    float h6 = h * (1.0f / 6.0f);
    y0v = fmaf(h6, k10 + k40 + 2.0f * (k20 + k30), y0v);
    y1v = fmaf(h6, k11 + k41 + 2.0f * (k21 + k31), y1v);
    y2v = fmaf(h6, k12 + k42 + 2.0f * (k22 + k32), y2v);
    y3v = fmaf(h6, k13 + k43 + 2.0f * (k23 + k33), y3v);

    if (lane < 4) {
      float ov = (lane == 0) ? y0v : (lane == 1) ? y1v : (lane == 2) ? y2v : y3v;
      out[(size_t)(t + 1) * 4 + lane] = ov;
    }

    sp = sn;
    sn = snn;
  }
}

extern "C" void kernel_launch(void* const* d_in, const int* in_sizes, int n_in,
                              void* d_out, int out_size, void* d_ws, size_t ws_size,
                              hipStream_t stream) {
  const float* s_grid = (const float*)d_in[0];
  const float* y0 = (const float*)d_in[1];
  const float* Win = (const float*)d_in[2];
  const float* bin_ = (const float*)d_in[3];
  const float* W1a = (const float*)d_in[4];
  const float* b1a = (const float*)d_in[5];
  const float* W1b = (const float*)d_in[6];
  const float* b1b = (const float*)d_in[7];
  const float* W2a = (const float*)d_in[8];
  const float* b2a = (const float*)d_in[9];
  const float* W2b = (const float*)d_in[10];
  const float* b2b = (const float*)d_in[11];
  const float* Wout = (const float*)d_in[12];
  const float* bout = (const float*)d_in[13];
  const float* A = (const float*)d_in[14];
  int T = in_sizes[0];

  ode_kernel<<<1, 64, 0, stream>>>(s_grid, y0, Win, bin_, W1a, b1a, W1b, b1b,
                                   W2a, b2a, W2b, b2b, Wout, bout, A,
                                   (float*)d_out, T);
}

// Round 6
// 6676.816 us; speedup vs baseline: 1.2400x; 1.2400x over previous
//
#include <hip/hip_runtime.h>

// PopulationODE: sequential RK4 scan, T=4096, state=4, HID=32.
// One wave64, everything in registers, s_grid staged in LDS.
//
// Round-6: algebraic collapse of the residual blocks.
//   M21 = W2a*W1b, c2 = W2a*b1b + b2a  (precomputed in-kernel, one-time)
//   Wo1 = Wout*W1b, Wo2 = Wout*W2b, co = Wout*(b1b+b2b)+bout
//   u1 = W1a*x + b1a          ; t1 = tanh(u1)
//   u2 = W2a*x + M21*t1 + c2  ; t2 = tanh(u2)   (W2a*x off-path)
//   p  = Wout*x + Wo1*t1 + Wo2*t2 + co
// Critical path: 2 serial matvecs (was 4) + head per-lane FMA.
//
// Layouts (m = lane>>4, i = lane&15):
//   ABAB: lane holds v[16*(m&1) + i]; AABB: lane holds v[16*(m>>1) + i]
// matvecA: ABAB->AABB (p16swap combine); matvecB: AABB->ABAB (p32swap).
// relayout AABB->ABAB: p32swap dup + per-row select.

__device__ __forceinline__ float fexp2(float x) { return __builtin_amdgcn_exp2f(x); }
__device__ __forceinline__ float frcp(float x) { return __builtin_amdgcn_rcpf(x); }
__device__ __forceinline__ float ftanh_pre(float zs) {  // tanh(z), zs = 2*log2e*z
  float e = fexp2(zs);
  return 1.0f - 2.0f * frcp(e + 1.0f);
}
__device__ __forceinline__ float fsigm_pre(float zs) {  // sigm(z), zs = -log2e*z
  return frcp(1.0f + fexp2(zs));
}
__device__ __forceinline__ float fsigm(float a) {
  return frcp(1.0f + fexp2(a * -1.4426950408889634f));
}
#define C_TANH 2.8853900817779268f
#define C_NSIG (-1.4426950408889634f)

template<int CTRL>
__device__ __forceinline__ float dppmov(float x) {
  return __int_as_float(__builtin_amdgcn_update_dpp(
      0, __float_as_int(x), CTRL, 0xF, 0xF, true));
}
#define RORc(K) (0x120 | (K))

__device__ __forceinline__ void p16swap(float& a, float& b) {
  asm("s_nop 1\n\tv_permlane16_swap_b32 %0, %1" : "+v"(a), "+v"(b));
}
__device__ __forceinline__ void p32swap(float& a, float& b) {
  asm("s_nop 1\n\tv_permlane32_swap_b32 %0, %1" : "+v"(a), "+v"(b));
}

#define MV_CORE(W, BZ, X, SOUT) do {                                   \
    float a0_ = fmaf((X),                 W[0],  (BZ));                \
    float a1_ = dppmov<RORc(1)>(X)      * W[1];                        \
    float a2_ = dppmov<RORc(2)>(X)      * W[2];                        \
    float a3_ = dppmov<RORc(3)>(X)      * W[3];                        \
    a0_ = fmaf(dppmov<RORc(4)>(X),  W[4],  a0_);                       \
    a1_ = fmaf(dppmov<RORc(5)>(X),  W[5],  a1_);                       \
    a2_ = fmaf(dppmov<RORc(6)>(X),  W[6],  a2_);                       \
    a3_ = fmaf(dppmov<RORc(7)>(X),  W[7],  a3_);                       \
    a0_ = fmaf(dppmov<RORc(8)>(X),  W[8],  a0_);                       \
    a1_ = fmaf(dppmov<RORc(9)>(X),  W[9],  a1_);                       \
    a2_ = fmaf(dppmov<RORc(10)>(X), W[10], a2_);                       \
    a3_ = fmaf(dppmov<RORc(11)>(X), W[11], a3_);                       \
    a0_ = fmaf(dppmov<RORc(12)>(X), W[12], a0_);                       \
    a1_ = fmaf(dppmov<RORc(13)>(X), W[13], a1_);                       \
    a2_ = fmaf(dppmov<RORc(14)>(X), W[14], a2_);                       \
    a3_ = fmaf(dppmov<RORc(15)>(X), W[15], a3_);                       \
    SOUT = (a0_ + a1_) + (a2_ + a3_);                                  \
  } while (0)

__global__ __launch_bounds__(64, 1) __attribute__((amdgpu_waves_per_eu(1, 1)))
void ode_kernel(const float* __restrict__ s_grid,
                const float* __restrict__ y0in,
                const float* __restrict__ Win,
                const float* __restrict__ bin_,
                const float* __restrict__ W1a, const float* __restrict__ b1a,
                const float* __restrict__ W1b, const float* __restrict__ b1b,
                const float* __restrict__ W2a, const float* __restrict__ b2a,
                const float* __restrict__ W2b, const float* __restrict__ b2b,
                const float* __restrict__ Wout, const float* __restrict__ bout,
                const float* __restrict__ Aarr,
                float* __restrict__ out, int T) {
  const int lane = threadIdx.x;   // 0..63
  const int i = lane & 15;
  const int m = lane >> 4;        // row 0..3
  const int mlo = m & 1;
  const int mhi = m >> 1;

  // ---- stage s_grid into LDS (removes in-loop global loads) ----
  __shared__ float s_lds[8192];
  for (int idx = lane; idx < T && idx < 8192; idx += 64)
    s_lds[idx] = s_grid[idx];
  __syncthreads();

  // ---- direction probes ----
  int delta;
  {
    float pr = (float)i;
    float pr1 = dppmov<RORc(1)>(pr);
    delta = (((int)pr1) - i) & 15;
  }
  bool p32_c_low;
  {
    float v = (float)(lane >> 5);
    float c = v, d = v;
    p32swap(c, d);
    p32_c_low = (c == 0.0f);
  }

  // ---- weights (pre-scaled; M21 and head foldings precomputed) ----
  const int rA = 16 * mhi + i, hA = mlo;   // matvecA out-row / col-block
  const int rB = 16 * mlo + i, hB = mhi;   // matvecB out-row / col-block
  float w1a[16], w2a[16], m21[16];
#pragma unroll
  for (int k = 0; k < 16; ++k) {
    int cA = hA * 16 + ((i + delta * k) & 15);
    int cB = hB * 16 + ((i + delta * k) & 15);
    w1a[k] = W1a[rA * 32 + cA] * C_TANH;
    w2a[k] = W2a[rA * 32 + cA] * C_TANH;
    float acc = 0.0f;
    for (int q = 0; q < 32; ++q)
      acc = fmaf(W2a[rB * 32 + q], W1b[q * 32 + cB], acc);
    m21[k] = acc * C_TANH;                  // (W2a*W1b)[rB][cB] scaled
  }
  float bzm;                                 // c2 = W2a*b1b + b2a, on hB==0 lanes
  {
    float acc = b2a[rB];
    for (int q = 0; q < 32; ++q) acc = fmaf(W2a[rB * 32 + q], b1b[q], acc);
    bzm = hB ? 0.0f : acc * C_TANH;
  }
  float bz1a = hA ? 0.0f : b1a[rA] * C_TANH;

  const int r_in = 16 * mlo + i;             // input layer -> ABAB
  float winy0 = Win[r_in * 5 + 0] * C_TANH;
  float winy1 = Win[r_in * 5 + 1] * C_TANH;
  float winy2 = Win[r_in * 5 + 2] * C_TANH;
  float winy3 = Win[r_in * 5 + 3] * C_TANH;
  float wins  = Win[r_in * 5 + 4] * C_TANH;
  float binr  = bin_[r_in] * C_TANH;

  // head foldings: rows {2*mhi, 2*mhi+1}, element e1 = 16*mlo+i (ABAB)
  const int ra_ = 2 * mhi, rb_ = 2 * mhi + 1, e1 = r_in;
  float woXa = Wout[ra_ * 32 + e1] * C_NSIG;
  float woXb = Wout[rb_ * 32 + e1] * C_NSIG;
  float wo1a = 0.0f, wo1b = 0.0f, wo2a = 0.0f, wo2b = 0.0f;
  float bha = 0.0f, bhb = 0.0f;
  for (int q = 0; q < 32; ++q) {
    float wa = Wout[ra_ * 32 + q], wb = Wout[rb_ * 32 + q];
    float c1 = W1b[q * 32 + e1], c2c = W2b[q * 32 + e1];
    wo1a = fmaf(wa, c1, wo1a);  wo1b = fmaf(wb, c1, wo1b);
    wo2a = fmaf(wa, c2c, wo2a); wo2b = fmaf(wb, c2c, wo2b);
    float bs = b1b[q] + b2b[q];
    bha = fmaf(wa, bs, bha);    bhb = fmaf(wb, bs, bhb);
  }
  wo1a *= C_NSIG; wo1b *= C_NSIG; wo2a *= C_NSIG; wo2b *= C_NSIG;
  float boa = (bha + bout[ra_]) * (C_NSIG / 32.0f);
  float bob = (bhb + bout[rb_]) * (C_NSIG / 32.0f);
  float Aa = mhi ? Aarr[2] : Aarr[0];
  float Ab = mhi ? Aarr[3] : Aarr[1];
  const bool selhi = (mhi != 0);

  auto matvecA = [&](const float (&w)[16], float bz, float xin) -> float {
    float s; MV_CORE(w, bz, xin, s);
    float b = s; p16swap(s, b);
    return s + b;                  // AABB
  };
  auto matvecB = [&](const float (&w)[16], float bz, float xin) -> float {
    float s; MV_CORE(w, bz, xin, s);
    float b = s; p32swap(s, b);
    return s + b;                  // ABAB
  };
  auto relayout = [&](float v) -> float {    // AABB -> ABAB
    float c = v, d = v;
    p32swap(c, d);
    float lo = p32_c_low ? c : d;   // block-0 value everywhere
    float hi = p32_c_low ? d : c;   // block-1 value everywhere
    return mlo ? hi : lo;
  };

  auto feval = [&](float YA, float YB, float YC, float YD, float ZS,
                   float& K0, float& K1, float& K2, float& K3) {
    // off-path: prefactors
    float Ya = selhi ? YC : YA;
    float Yb = selhi ? YD : YB;
    float s_a = fsigm(Ya), s_b = fsigm(Yb);
    float pref_a = 0.01f * s_a * (Aa - s_a);
    float pref_b = 0.01f * s_b * (Ab - s_b);
    // input layer
    float za = fmaf(winy0, YA, ZS);
    float zb = winy1 * YB;
    float zc = winy2 * YC;
    float zd = winy3 * YD;
    float z = (za + zb) + (zc + zd);
    float x = ftanh_pre(z);                     // ABAB
    // block 1 (on path) and W2a*x (off path, parallel)
    float u1 = matvecA(w1a, bz1a, x);           // AABB
    float q2 = matvecA(w2a, 0.0f, x);           // AABB (off-path)
    float t1 = ftanh_pre(u1);                   // AABB
    float q2r = relayout(q2);                   // ABAB (off-path)
    float t1r = relayout(t1);                   // ABAB (off-path, head)
    float r1 = matvecB(m21, bzm, t1);           // ABAB (on path)
    float u2 = r1 + q2r;
    float t2 = ftanh_pre(u2);                   // ABAB
    // head: x/t1 partials issue early; only the t2 FMA is on-path
    float p0 = fmaf(woXa, x, boa);
    float p1 = fmaf(woXb, x, bob);
    p0 = fmaf(wo1a, t1r, p0);
    p1 = fmaf(wo1b, t1r, p1);
    p0 = fmaf(wo2a, t2, p0);
    p1 = fmaf(wo2b, t2, p1);
    p0 += dppmov<RORc(8)>(p0); p1 += dppmov<RORc(8)>(p1);
    p0 += dppmov<RORc(4)>(p0); p1 += dppmov<RORc(4)>(p1);
    p0 += dppmov<RORc(2)>(p0); p1 += dppmov<RORc(2)>(p1);
    p0 += dppmov<RORc(1)>(p0); p1 += dppmov<RORc(1)>(p1);
    float q0 = p0; p16swap(p0, q0); p0 += q0;   // rows0,1:P0'  rows2,3:P2'
    float q1 = p1; p16swap(p1, q1); p1 += q1;   // rows0,1:P1'  rows2,3:P3'
    float n_a = fsigm_pre(p0);
    float n_b = fsigm_pre(p1);
    float Ka = pref_a * n_a;      // rows0,1: K0   rows2,3: K2
    float Kb = pref_b * n_b;      // rows0,1: K1   rows2,3: K3
    float c0 = Ka, d0 = Ka; p32swap(c0, d0);
    K0 = p32_c_low ? c0 : d0;
    K2 = p32_c_low ? d0 : c0;
    float c1 = Kb, d1 = Kb; p32swap(c1, d1);
    K1 = p32_c_low ? c1 : d1;
    K3 = p32_c_low ? d1 : c1;
  };

  // ---- state ----
  float y0v = y0in[0], y1v = y0in[1], y2v = y0in[2], y3v = y0in[3];

  if (lane < 4) {
    float ov = (lane == 0) ? y0v : (lane == 1) ? y1v : (lane == 2) ? y2v : y3v;
    out[lane] = ov;
  }

  float sp = s_lds[0];
  float sn = s_lds[1];

  for (int t = 0; t < T - 1; ++t) {
    int tn = (t + 2 < T) ? (t + 2) : (T - 1);
    float snn = s_lds[tn];             // LDS read, hidden under the step
    float h = sn - sp;
    float zs = fmaf(wins, sp, binr);   // shared by all 4 stages

    float k0, k1, k2, k3;              // current-stage K
    float a0, a1, a2, a3;              // running RK accumulators

    feval(y0v, y1v, y2v, y3v, zs, k0, k1, k2, k3);
    a0 = k0; a1 = k1; a2 = k2; a3 = k3;

    float hh = 0.5f * h;
    float ya0 = fmaf(hh, k0, y0v), ya1 = fmaf(hh, k1, y1v);
    float ya2 = fmaf(hh, k2, y2v), ya3 = fmaf(hh, k3, y3v);
    feval(ya0, ya1, ya2, ya3, zs, k0, k1, k2, k3);
    a0 = fmaf(2.0f, k0, a0); a1 = fmaf(2.0f, k1, a1);
    a2 = fmaf(2.0f, k2, a2); a3 = fmaf(2.0f, k3, a3);

    float yb0 = fmaf(hh, k0, y0v), yb1 = fmaf(hh, k1, y1v);
    float yb2 = fmaf(hh, k2, y2v), yb3 = fmaf(hh, k3, y3v);
    feval(yb0, yb1, yb2, yb3, zs, k0, k1, k2, k3);
    a0 = fmaf(2.0f, k0, a0); a1 = fmaf(2.0f, k1, a1);
    a2 = fmaf(2.0f, k2, a2); a3 = fmaf(2.0f, k3, a3);

    float yc0 = fmaf(h, k0, y0v), yc1 = fmaf(h, k1, y1v);
    float yc2 = fmaf(h, k2, y2v), yc3 = fmaf(h, k3, y3v);
    feval(yc0, yc1, yc2, yc3, zs, k0, k1, k2, k3);
    a0 += k0; a1 += k1; a2 += k2; a3 += k3;

    float h6 = h * (1.0f / 6.0f);
    y0v = fmaf(h6, a0, y0v);
    y1v = fmaf(h6, a1, y1v);
    y2v = fmaf(h6, a2, y2v);
    y3v = fmaf(h6, a3, y3v);

    if (lane < 4) {
      float ov = (lane == 0) ? y0v : (lane == 1) ? y1v : (lane == 2) ? y2v : y3v;
      out[(size_t)(t + 1) * 4 + lane] = ov;
    }

    sp = sn;
    sn = snn;
  }
}

extern "C" void kernel_launch(void* const* d_in, const int* in_sizes, int n_in,
                              void* d_out, int out_size, void* d_ws, size_t ws_size,
                              hipStream_t stream) {
  const float* s_grid = (const float*)d_in[0];
  const float* y0 = (const float*)d_in[1];
  const float* Win = (const float*)d_in[2];
  const float* bin_ = (const float*)d_in[3];
  const float* W1a = (const float*)d_in[4];
  const float* b1a = (const float*)d_in[5];
  const float* W1b = (const float*)d_in[6];
  const float* b1b = (const float*)d_in[7];
  const float* W2a = (const float*)d_in[8];
  const float* b2a = (const float*)d_in[9];
  const float* W2b = (const float*)d_in[10];
  const float* b2b = (const float*)d_in[11];
  const float* Wout = (const float*)d_in[12];
  const float* bout = (const float*)d_in[13];
  const float* A = (const float*)d_in[14];
  int T = in_sizes[0];

  ode_kernel<<<1, 64, 0, stream>>>(s_grid, y0, Win, bin_, W1a, b1a, W1b, b1b,
                                   W2a, b2a, W2b, b2b, Wout, bout, A,
                                   (float*)d_out, T);
}

// Round 7
// 5839.177 us; speedup vs baseline: 1.4179x; 1.1435x over previous
//
#include <hip/hip_runtime.h>

// PopulationODE: sequential RK4 scan, T=4096, state=4, HID=32.
// One wave64; latency-bound serial chain => minimize ops ON the chain.
//
// g-form network: every tanh(u) = 1-2g with g = rcp(exp2(u')+1) and the
// affine (1-2g) folded into downstream weights/biases (rowsum folds).
// Collapsed residuals: u2 = W2a*x + M21*t1 + c2 with M21=W2a*W1b;
// head p = Wout*x + Wo1*t1 + Wo2*t2 + co, all in g-form.
// Next-stage input via gk = Winy.K (row-pair partials + p32swap), so the
// K broadcast is fully off the critical path. zb carried incrementally.
//
// Layouts (m = lane>>4, i = lane&15):
//   ABAB: lane holds v[16*(m&1)+i]; AABB: lane holds v[16*(m>>1)+i]
// matvecA: ABAB->AABB (p16swap); matvecB: AABB->ABAB (p32swap).

__device__ __forceinline__ float fexp2(float x) { return __builtin_amdgcn_exp2f(x); }
__device__ __forceinline__ float frcp(float x) { return __builtin_amdgcn_rcpf(x); }
#define C_TANH 2.8853900817779268f
#define C_NSIG (-1.4426950408889634f)

template<int CTRL>
__device__ __forceinline__ float dppmov(float x) {
  return __int_as_float(__builtin_amdgcn_update_dpp(
      0, __float_as_int(x), CTRL, 0xF, 0xF, true));
}
#define RORc(K) (0x120 | (K))

__device__ __forceinline__ void p16swap(float& a, float& b) {
  asm("s_nop 1\n\tv_permlane16_swap_b32 %0, %1" : "+v"(a), "+v"(b));
}
__device__ __forceinline__ void p32swap(float& a, float& b) {
  asm("s_nop 1\n\tv_permlane32_swap_b32 %0, %1" : "+v"(a), "+v"(b));
}

// 8 streams x depth-2 MACs + depth-3 tree (serial depth 5).
#define MV8(W, BZ, X, SOUT) do {                                       \
    float b0_ = fmaf((X),             W[0], (BZ));                     \
    float b1_ = dppmov<RORc(1)>(X)  * W[1];                            \
    float b2_ = dppmov<RORc(2)>(X)  * W[2];                            \
    float b3_ = dppmov<RORc(3)>(X)  * W[3];                            \
    float b4_ = dppmov<RORc(4)>(X)  * W[4];                            \
    float b5_ = dppmov<RORc(5)>(X)  * W[5];                            \
    float b6_ = dppmov<RORc(6)>(X)  * W[6];                            \
    float b7_ = dppmov<RORc(7)>(X)  * W[7];                            \
    b0_ = fmaf(dppmov<RORc(8)>(X),  W[8],  b0_);                       \
    b1_ = fmaf(dppmov<RORc(9)>(X),  W[9],  b1_);                       \
    b2_ = fmaf(dppmov<RORc(10)>(X), W[10], b2_);                       \
    b3_ = fmaf(dppmov<RORc(11)>(X), W[11], b3_);                       \
    b4_ = fmaf(dppmov<RORc(12)>(X), W[12], b4_);                       \
    b5_ = fmaf(dppmov<RORc(13)>(X), W[13], b5_);                       \
    b6_ = fmaf(dppmov<RORc(14)>(X), W[14], b6_);                       \
    b7_ = fmaf(dppmov<RORc(15)>(X), W[15], b7_);                       \
    SOUT = ((b0_ + b1_) + (b2_ + b3_)) + ((b4_ + b5_) + (b6_ + b7_));  \
  } while (0)

__global__ __launch_bounds__(64, 1) __attribute__((amdgpu_waves_per_eu(1, 1)))
void ode_kernel(const float* __restrict__ s_grid,
                const float* __restrict__ y0in,
                const float* __restrict__ Win,
                const float* __restrict__ bin_,
                const float* __restrict__ W1a, const float* __restrict__ b1a,
                const float* __restrict__ W1b, const float* __restrict__ b1b,
                const float* __restrict__ W2a, const float* __restrict__ b2a,
                const float* __restrict__ W2b, const float* __restrict__ b2b,
                const float* __restrict__ Wout, const float* __restrict__ bout,
                const float* __restrict__ Aarr,
                float* __restrict__ out, int T) {
  const int lane = threadIdx.x;
  const int i = lane & 15;
  const int m = lane >> 4;
  const int mlo = m & 1;
  const int mhi = m >> 1;

  // ---- stage s_grid into LDS ----
  __shared__ float s_lds[4096];
  for (int idx = lane; idx < T && idx < 4096; idx += 64)
    s_lds[idx] = s_grid[idx];
  __syncthreads();

  // ---- direction probes ----
  int delta;
  {
    float pr = (float)i;
    float pr1 = dppmov<RORc(1)>(pr);
    delta = (((int)pr1) - i) & 15;
  }
  bool p32_c_low;
  {
    float v = (float)(lane >> 5);
    float c = v, d = v;
    p32swap(c, d);
    p32_c_low = (c == 0.0f);
  }

  // ---- weight prep (one-time) ----
  const int rA = 16 * mhi + i, hA = mlo;   // matvecA out-row / col-block
  const int rB = 16 * mlo + i, hB = mhi;   // matvecB out-row / col-block
  const int r_in = 16 * mlo + i;           // ABAB element owned by lane
  const int e1 = r_in;

  float w1a[16], w2a[16], m21[16];
#pragma unroll 1
  for (int k = 0; k < 16; ++k) {
    int cA = hA * 16 + ((i + delta * k) & 15);
    int cB = hB * 16 + ((i + delta * k) & 15);
    w1a[k] = W1a[rA * 32 + cA] * (-2.0f * C_TANH);
    w2a[k] = W2a[rA * 32 + cA] * (-2.0f * C_TANH);
    float acc = 0.0f;
    for (int q = 0; q < 32; ++q)
      acc = fmaf(W2a[rB * 32 + q], W1b[q * 32 + cB], acc);
    m21[k] = acc * (-2.0f * C_TANH);
  }
  // bz1a'' = C_TANH*(b1a + rowsum(W1a)) on hA==0 lanes
  float bz1a;
  {
    float rs = 0.0f;
    for (int c = 0; c < 32; ++c) rs += W1a[rA * 32 + c];
    bz1a = hA ? 0.0f : C_TANH * (b1a[rA] + rs);
  }
  // c2'' = C_TANH*(rowsum(W2a) + rowsum(M21) + W2a.b1b + b2a) on hB==0 lanes
  float c2sel;
  {
    float rs2a = 0.0f, m21rs = 0.0f, wb = 0.0f;
    for (int q = 0; q < 32; ++q) {
      float w2q = W2a[rB * 32 + q];
      rs2a += w2q;
      float rs1bq = 0.0f;
      for (int c = 0; c < 32; ++c) rs1bq += W1b[q * 32 + c];
      m21rs = fmaf(w2q, rs1bq, m21rs);
      wb = fmaf(w2q, b1b[q], wb);
    }
    c2sel = hB ? 0.0f : C_TANH * (rs2a + m21rs + wb + b2a[rB]);
  }
  const bool seedsel = (mlo == mhi);   // rows 0,3 carry the q2 seed

  // input layer (pre-scaled by C_TANH)
  float winy0 = Win[r_in * 5 + 0] * C_TANH;
  float winy1 = Win[r_in * 5 + 1] * C_TANH;
  float winy2 = Win[r_in * 5 + 2] * C_TANH;
  float winy3 = Win[r_in * 5 + 3] * C_TANH;
  float wins  = Win[r_in * 5 + 4] * C_TANH;
  float binr  = bin_[r_in] * C_TANH;
  float gsel_a = mhi ? winy2 : winy0;   // gk partial weights for this row
  float gsel_b = mhi ? winy3 : winy1;

  // head (rows ra_=2*mhi, rb_=2*mhi+1), g-form + rowsum folds
  const int ra_ = 2 * mhi, rb_ = 2 * mhi + 1;
  float woXa = Wout[ra_ * 32 + e1] * (-2.0f * C_NSIG);
  float woXb = Wout[rb_ * 32 + e1] * (-2.0f * C_NSIG);
  float wo1a, wo1b, wo2a, wo2b, boa, bob;
  {
    float w1s_a = 0.0f, w1s_b = 0.0f, w2s_a = 0.0f, w2s_b = 0.0f;
    float rsX_a = 0.0f, rsX_b = 0.0f, rs1_a = 0.0f, rs1_b = 0.0f;
    float rs2_a = 0.0f, rs2_b = 0.0f, bt_a = 0.0f, bt_b = 0.0f;
    for (int q = 0; q < 32; ++q) {
      float waq = Wout[ra_ * 32 + q], wbq = Wout[rb_ * 32 + q];
      w1s_a = fmaf(waq, W1b[q * 32 + e1], w1s_a);
      w1s_b = fmaf(wbq, W1b[q * 32 + e1], w1s_b);
      w2s_a = fmaf(waq, W2b[q * 32 + e1], w2s_a);
      w2s_b = fmaf(wbq, W2b[q * 32 + e1], w2s_b);
      rsX_a += waq; rsX_b += wbq;
      float rs1bq = 0.0f, rs2bq = 0.0f;
      for (int c = 0; c < 32; ++c) {
        rs1bq += W1b[q * 32 + c];
        rs2bq += W2b[q * 32 + c];
      }
      rs1_a = fmaf(waq, rs1bq, rs1_a); rs1_b = fmaf(wbq, rs1bq, rs1_b);
      rs2_a = fmaf(waq, rs2bq, rs2_a); rs2_b = fmaf(wbq, rs2bq, rs2_b);
      float bs = b1b[q] + b2b[q];
      bt_a = fmaf(waq, bs, bt_a); bt_b = fmaf(wbq, bs, bt_b);
    }
    wo1a = w1s_a * (-2.0f * C_NSIG); wo1b = w1s_b * (-2.0f * C_NSIG);
    wo2a = w2s_a * (-2.0f * C_NSIG); wo2b = w2s_b * (-2.0f * C_NSIG);
    boa = (bout[ra_] + bt_a + rsX_a + rs1_a + rs2_a) * (C_NSIG / 32.0f);
    bob = (bout[rb_] + bt_b + rsX_b + rs1_b + rs2_b) * (C_NSIG / 32.0f);
  }
  float Aa = mhi ? Aarr[2] : Aarr[0];
  float Ab = mhi ? Aarr[3] : Aarr[1];

  // AABB -> ABAB relayout (off-path use only)
  auto relayout = [&](float v) -> float {
    float c = v, d = v;
    p32swap(c, d);
    float lo = p32_c_low ? c : d;
    float hi = p32_c_low ? d : c;
    return mlo ? hi : lo;
  };

  // one f(y,s) evaluation in g-form; wpa/wpb = gsel*pref (precomputed)
  auto stage = [&](float zin, float wpa, float wpb,
                   float& n_a, float& n_b, float& gk) {
    float g0 = frcp(fexp2(zin) + 1.0f);                    // ABAB
    float u1; MV8(w1a, bz1a, g0, u1);
    { float b = u1; p16swap(u1, b); u1 += b; }             // AABB
    float q2; MV8(w2a, 0.0f, g0, q2);
    { float b = q2; p16swap(q2, b); q2 += b; }             // AABB (off)
    float g1 = frcp(fexp2(u1) + 1.0f);                     // AABB
    float g1r = relayout(g1);                              // off
    float seed = (seedsel ? q2 : 0.0f) + c2sel;            // off
    float u2; MV8(m21, seed, g1, u2);
    { float b = u2; p32swap(u2, b); u2 += b; }             // ABAB
    float g2 = frcp(fexp2(u2) + 1.0f);
    float ph0 = fmaf(wo1a, g1r, fmaf(woXa, g0, boa));      // off
    float ph1 = fmaf(wo1b, g1r, fmaf(woXb, g0, bob));      // off
    float p0 = fmaf(wo2a, g2, ph0);
    float p1 = fmaf(wo2b, g2, ph1);
    p0 += dppmov<RORc(8)>(p0); p1 += dppmov<RORc(8)>(p1);
    p0 += dppmov<RORc(4)>(p0); p1 += dppmov<RORc(4)>(p1);
    p0 += dppmov<RORc(2)>(p0); p1 += dppmov<RORc(2)>(p1);
    p0 += dppmov<RORc(1)>(p0); p1 += dppmov<RORc(1)>(p1);
    { float q = p0; p16swap(p0, q); p0 += q; }
    { float q = p1; p16swap(p1, q); p1 += q; }
    n_a = frcp(1.0f + fexp2(p0));
    n_b = frcp(1.0f + fexp2(p1));
    float gp = fmaf(wpb, n_b, wpa * n_a);
    float gq = gp;
    p32swap(gp, gq);
    gk = gp + gq;
  };

  // ---- state: per-lane components a,b = (y0,y1) rows 0,1 / (y2,y3) rows 2,3
  float y00 = y0in[0], y01 = y0in[1], y02 = y0in[2], y03 = y0in[3];
  float ya = mhi ? y02 : y00;
  float yb = mhi ? y03 : y01;

  // initial output store: lanes {0,1,32,33} -> components 0..3
  if ((lane & 0x1E) == 0)
    out[(lane >> 4) + (lane & 1)] = (lane & 1) ? yb : ya;

  float sp = s_lds[0];
  float sn = (T > 1) ? s_lds[1] : sp;

  // zb = Winy'.y0 + wins'*s0 + binr'
  float zb = fmaf(winy0, y00, fmaf(winy1, y01, fmaf(winy2, y02,
             fmaf(winy3, y03, fmaf(wins, sp, binr)))));

  // initial prefactors
  float s_a = frcp(1.0f + fexp2(ya * C_NSIG));
  float s_b = frcp(1.0f + fexp2(yb * C_NSIG));
  float pref_a = 0.01f * s_a * (Aa - s_a);
  float pref_b = 0.01f * s_b * (Ab - s_b);
  float wp_a = gsel_a * pref_a, wp_b = gsel_b * pref_b;

  for (int t = 0; t < T - 1; ++t) {
    int tn = (t + 2 < T) ? (t + 2) : (T - 1);
    float snn = s_lds[tn < 4096 ? tn : 4095];
    float h = sn - sp;
    float hh = 0.5f * h;
    float h6 = h * (1.0f / 6.0f);
    float zbw = fmaf(wins, h, zb);       // off-path

    float na, nb, gk1, gk2, gk3, gk4;

    // ---- stage 1 ----
    stage(zb, wp_a, wp_b, na, nb, gk1);
    float z2 = fmaf(hh, gk1, zb);
    float Ka = pref_a * na, Kb = pref_b * nb;            // off
    float aa = Ka, ab = Kb;
    {
      float y1a = fmaf(hh, Ka, ya), y1b = fmaf(hh, Kb, yb);
      float sa = frcp(1.0f + fexp2(y1a * C_NSIG));
      float sb = frcp(1.0f + fexp2(y1b * C_NSIG));
      pref_a = 0.01f * sa * (Aa - sa); pref_b = 0.01f * sb * (Ab - sb);
      wp_a = gsel_a * pref_a; wp_b = gsel_b * pref_b;
    }

    // ---- stage 2 ----
    stage(z2, wp_a, wp_b, na, nb, gk2);
    float z3 = fmaf(hh, gk2, zb);
    Ka = pref_a * na; Kb = pref_b * nb;
    aa = fmaf(2.0f, Ka, aa); ab = fmaf(2.0f, Kb, ab);
    {
      float y2a = fmaf(hh, Ka, ya), y2b = fmaf(hh, Kb, yb);
      float sa = frcp(1.0f + fexp2(y2a * C_NSIG));
      float sb = frcp(1.0f + fexp2(y2b * C_NSIG));
      pref_a = 0.01f * sa * (Aa - sa); pref_b = 0.01f * sb * (Ab - sb);
      wp_a = gsel_a * pref_a; wp_b = gsel_b * pref_b;
    }

    // ---- stage 3 ----
    stage(z3, wp_a, wp_b, na, nb, gk3);
    float z4 = fmaf(h, gk3, zb);
    Ka = pref_a * na; Kb = pref_b * nb;
    aa = fmaf(2.0f, Ka, aa); ab = fmaf(2.0f, Kb, ab);
    float gacc = fmaf(2.0f, gk2, gk1);
    gacc = fmaf(2.0f, gk3, gacc);
    {
      float y3a = fmaf(h, Ka, ya), y3b = fmaf(h, Kb, yb);
      float sa = frcp(1.0f + fexp2(y3a * C_NSIG));
      float sb = frcp(1.0f + fexp2(y3b * C_NSIG));
      pref_a = 0.01f * sa * (Aa - sa); pref_b = 0.01f * sb * (Ab - sb);
      wp_a = gsel_a * pref_a; wp_b = gsel_b * pref_b;
    }

    // ---- stage 4 ----
    stage(z4, wp_a, wp_b, na, nb, gk4);
    float ag = gacc + gk4;
    zb = fmaf(h6, ag, zbw);                              // next step's zb
    Ka = pref_a * na; Kb = pref_b * nb;
    aa += Ka; ab += Kb;
    ya = fmaf(h6, aa, ya);
    yb = fmaf(h6, ab, yb);
    {
      float sa = frcp(1.0f + fexp2(ya * C_NSIG));
      float sb = frcp(1.0f + fexp2(yb * C_NSIG));
      pref_a = 0.01f * sa * (Aa - sa); pref_b = 0.01f * sb * (Ab - sb);
      wp_a = gsel_a * pref_a; wp_b = gsel_b * pref_b;
    }

    if ((lane & 0x1E) == 0)
      out[(size_t)(t + 1) * 4 + (lane >> 4) + (lane & 1)] = (lane & 1) ? yb : ya;

    sp = sn;
    sn = snn;
  }
}

extern "C" void kernel_launch(void* const* d_in, const int* in_sizes, int n_in,
                              void* d_out, int out_size, void* d_ws, size_t ws_size,
                              hipStream_t stream) {
  const float* s_grid = (const float*)d_in[0];
  const float* y0 = (const float*)d_in[1];
  const float* Win = (const float*)d_in[2];
  const float* bin_ = (const float*)d_in[3];
  const float* W1a = (const float*)d_in[4];
  const float* b1a = (const float*)d_in[5];
  const float* W1b = (const float*)d_in[6];
  const float* b1b = (const float*)d_in[7];
  const float* W2a = (const float*)d_in[8];
  const float* b2a = (const float*)d_in[9];
  const float* W2b = (const float*)d_in[10];
  const float* b2b = (const float*)d_in[11];
  const float* Wout = (const float*)d_in[12];
  const float* bout = (const float*)d_in[13];
  const float* A = (const float*)d_in[14];
  int T = in_sizes[0];

  ode_kernel<<<1, 64, 0, stream>>>(s_grid, y0, Win, bin_, W1a, b1a, W1b, b1b,
                                   W2a, b2a, W2b, b2b, Wout, bout, A,
                                   (float*)d_out, T);
}